// Round 1
// baseline (158.258 us; speedup 1.0000x reference)
//
#include <hip/hip_runtime.h>
#include <stdint.h>

typedef unsigned int uint;
typedef unsigned short ushort;

#define NB_FEATURES 512
#define MB_DIM      10240
#define NB_CLASSES  100
#define BATCH       8192
#define KSEL        32
#define VPT         40    // MB_DIM / 256 values per thread

static __device__ __forceinline__ uint f2key(float f) {
    uint u = __float_as_uint(f);
    return u ^ (0x80000000u | (uint)((int)u >> 31));  // monotonic: larger float -> larger uint
}
static __device__ __forceinline__ float key2f(uint k) {
    uint u = k ^ (0x80000000u | (uint)(((int)~k) >> 31));
    return __uint_as_float(u);
}

// ---------------------------------------------------------------------------
// Kernel A: extract per-row nonzero column indices of w1 (values are 0.0/1.0).
// One wave per row. Deterministic slot assignment via wave prefix scan.
// Slots padded with NB_FEATURES (=512) which indexes a zeroed LDS entry.
// ---------------------------------------------------------------------------
__global__ __launch_bounds__(256) void k_extract(const float* __restrict__ w1,
                                                 ushort* __restrict__ idx) {
    const int gw   = (blockIdx.x * 256 + threadIdx.x) >> 6;  // global wave id = row
    const int lane = threadIdx.x & 63;
    if (gw >= MB_DIM) return;
    const float* row = w1 + (size_t)gw * NB_FEATURES;
    const float4 a = *(const float4*)(row + lane * 8);
    const float4 b = *(const float4*)(row + lane * 8 + 4);
    const float v[8] = {a.x, a.y, a.z, a.w, b.x, b.y, b.z, b.w};
    int cnt = 0;
#pragma unroll
    for (int j = 0; j < 8; ++j) cnt += (v[j] > 0.5f);
    int p = cnt;
#pragma unroll
    for (int off = 1; off < 64; off <<= 1) {
        int n = __shfl_up(p, off, 64);
        if (lane >= off) p += n;
    }
    const int total = __shfl(p, 63, 64);
    int slot = p - cnt;  // exclusive prefix
    ushort* dst = idx + (size_t)gw * 8;
#pragma unroll
    for (int j = 0; j < 8; ++j) {
        if (v[j] > 0.5f) {
            if (slot < 8) dst[slot] = (ushort)(lane * 8 + j);
            slot++;
        }
    }
    if (lane >= total && lane < 8) dst[lane] = (ushort)NB_FEATURES;  // pad
}

// ---------------------------------------------------------------------------
// Kernel B: w2t[m][c] = max(w2[c][m], 0)  (transpose+clamp for coalesced gather)
// ---------------------------------------------------------------------------
__global__ __launch_bounds__(256) void k_w2t(const float* __restrict__ w2,
                                             float* __restrict__ w2t) {
    const int i = blockIdx.x * 256 + threadIdx.x;
    if (i >= NB_CLASSES * MB_DIM) return;
    const int c = i / MB_DIM;
    const int m = i - c * MB_DIM;
    w2t[(size_t)m * NB_CLASSES + c] = fmaxf(w2[i], 0.0f);
}

// ---------------------------------------------------------------------------
// Kernel C: one block (256 threads) per batch row.
// ---------------------------------------------------------------------------
template <bool USE_W2T>
__global__ __launch_bounds__(256) void k_main(
    const float* __restrict__ x, const ushort* __restrict__ idx,
    const float* __restrict__ w2t, const float* __restrict__ w2,
    const float* __restrict__ b2, float* __restrict__ out)
{
    __shared__ float xs[NB_FEATURES + 4];
    __shared__ uint  cand[512];
    __shared__ uint  s_wsum[4];
    __shared__ uint  s_piv[4];
    __shared__ uint  s_thkey;
    __shared__ uint  s_cnt1;
    __shared__ uint  s_pref;
    __shared__ int   s_k;
    __shared__ uint  list_m[64];
    __shared__ float list_v[64];

    const int tid  = threadIdx.x;
    const int lane = tid & 63;
    const int wid  = tid >> 6;
    const int brow = blockIdx.x;

    // 1. stage x row in LDS (+ zero pad at index 512)
    {
        const float2 v = *(const float2*)(x + (size_t)brow * NB_FEATURES + tid * 2);
        *(float2*)(xs + tid * 2) = v;
        if (tid < 4) xs[NB_FEATURES + tid] = 0.0f;
    }
    __syncthreads();

    // 2. compute h (sum of <=8 gathered x entries) -> monotonic uint keys in regs
    uint key[VPT];
#pragma unroll
    for (int i = 0; i < VPT; ++i) {
        const int m = tid + (i << 8);
        const uint4 q = *(const uint4*)(idx + ((size_t)m << 3));
        float s = xs[q.x & 0xFFFFu] + xs[q.x >> 16]
                + xs[q.y & 0xFFFFu] + xs[q.y >> 16]
                + xs[q.z & 0xFFFFu] + xs[q.z >> 16]
                + xs[q.w & 0xFFFFu] + xs[q.w >> 16];
        key[i] = f2key(s);
    }

    // 3. pivot: per-thread max -> per-wave bitonic sort(64) -> wave's rank-31 ->
    //    pivot = max over waves (provably <= true 32nd-largest)
    {
        uint v = key[0];
#pragma unroll
        for (int i = 1; i < VPT; ++i) v = max(v, key[i]);
#pragma unroll
        for (int k = 2; k <= 64; k <<= 1) {
#pragma unroll
            for (int j = k >> 1; j > 0; j >>= 1) {
                const uint pr = __shfl_xor(v, j, 64);
                const bool lower = (lane & j) == 0;
                const bool asc   = (lane & k) == 0;
                const uint mn = min(v, pr), mx = max(v, pr);
                v = (lower == asc) ? mx : mn;  // descending sort
            }
        }
        if (lane == 31) s_piv[wid] = v;
    }
    __syncthreads();
    const uint pivot = max(max(s_piv[0], s_piv[1]), max(s_piv[2], s_piv[3]));

    // 4. compact candidate keys (>= pivot) into LDS, deterministic order
    int myc = 0;
#pragma unroll
    for (int i = 0; i < VPT; ++i) myc += (key[i] >= pivot) ? 1 : 0;
    int p = myc;
#pragma unroll
    for (int off = 1; off < 64; off <<= 1) {
        int n = __shfl_up(p, off, 64);
        if (lane >= off) p += n;
    }
    if (lane == 63) s_wsum[wid] = (uint)p;
    __syncthreads();
    int base = p - myc;
    for (int w = 0; w < wid; ++w) base += (int)s_wsum[w];
    const int ctot = (int)(s_wsum[0] + s_wsum[1] + s_wsum[2] + s_wsum[3]);
    {
        int slot = base;
#pragma unroll
        for (int i = 0; i < VPT; ++i) {
            if (key[i] >= pivot) {
                if (slot < 512) cand[slot] = key[i];
                slot++;
            }
        }
    }
    __syncthreads();

    // 5. exact 32nd-largest key (threshold). Ties handled like the reference
    //    (h >= th keeps all tied). Fallback radix for pathological tie floods.
    if (ctot <= 512) {
        if (tid < ctot) {
            const uint u = cand[tid];
            int rank = 0;
            for (int j = 0; j < ctot; ++j) {
                const uint vv = cand[j];
                rank += ((vv > u) || (vv == u && j < tid)) ? 1 : 0;
            }
            if (rank == KSEL - 1) s_thkey = u;
        }
    } else {
        if (tid == 0) { s_pref = 0u; s_k = KSEL; }
        __syncthreads();
        for (int bit = 31; bit >= 0; --bit) {
            const uint bmask = 1u << bit;
            const uint dmask = (bit == 31) ? 0u : (0xFFFFFFFFu << (bit + 1));
            const uint pref = s_pref;
            int mc = 0;
#pragma unroll
            for (int i = 0; i < VPT; ++i)
                mc += (((key[i] & dmask) == pref) && (key[i] & bmask)) ? 1 : 0;
            if (tid == 0) s_cnt1 = 0;
            __syncthreads();
            if (mc) atomicAdd(&s_cnt1, (uint)mc);
            __syncthreads();
            if (tid == 0) {
                if ((int)s_cnt1 >= s_k) s_pref = pref | bmask;
                else s_k -= (int)s_cnt1;
            }
            __syncthreads();
        }
        if (tid == 0) s_thkey = s_pref;
    }
    __syncthreads();
    const uint thkey = s_thkey;

    // 6. final compaction of kept entries (key >= thkey) with (m, value)
    int kc = 0;
#pragma unroll
    for (int i = 0; i < VPT; ++i) kc += (key[i] >= thkey) ? 1 : 0;
    int p2 = kc;
#pragma unroll
    for (int off = 1; off < 64; off <<= 1) {
        int n = __shfl_up(p2, off, 64);
        if (lane >= off) p2 += n;
    }
    if (lane == 63) s_wsum[wid] = (uint)p2;
    __syncthreads();
    int kbase = p2 - kc;
    for (int w = 0; w < wid; ++w) kbase += (int)s_wsum[w];
    const int ktot = (int)(s_wsum[0] + s_wsum[1] + s_wsum[2] + s_wsum[3]);
    {
        int slot = kbase;
#pragma unroll
        for (int i = 0; i < VPT; ++i) {
            if (key[i] >= thkey) {
                if (slot < 64) {
                    list_m[slot] = (uint)(tid + (i << 8));
                    list_v[slot] = key2f(key[i]);
                }
                slot++;
            }
        }
    }
    __syncthreads();

    // 7. out[b][c] = b2[c] + sum_j v_j * max(w2[c][m_j],0)
    const int cnt = ktot < 64 ? ktot : 64;
    if (tid < NB_CLASSES) {
        float acc = b2[tid];
        for (int j = 0; j < cnt; ++j) {
            const uint m = list_m[j];
            const float w = USE_W2T ? w2t[(size_t)m * NB_CLASSES + tid]
                                    : fmaxf(w2[(size_t)tid * MB_DIM + m], 0.0f);
            acc = fmaf(list_v[j], w, acc);
        }
        out[(size_t)brow * NB_CLASSES + tid] = acc;
    }
}

// ---------------------------------------------------------------------------
extern "C" void kernel_launch(void* const* d_in, const int* in_sizes, int n_in,
                              void* d_out, int out_size, void* d_ws, size_t ws_size,
                              hipStream_t stream) {
    const float* x  = (const float*)d_in[0];
    const float* w1 = (const float*)d_in[1];
    const float* w2 = (const float*)d_in[2];
    const float* b2 = (const float*)d_in[3];
    float* out = (float*)d_out;

    ushort* idx = (ushort*)d_ws;                       // 10240*8*2 = 160 KB
    const size_t W2T_OFF = 262144;                     // 256 KB aligned
    float* w2t = (float*)((char*)d_ws + W2T_OFF);
    const bool use_w2t =
        ws_size >= W2T_OFF + (size_t)MB_DIM * NB_CLASSES * sizeof(float);

    k_extract<<<(MB_DIM * 64) / 256, 256, 0, stream>>>(w1, idx);
    if (use_w2t) {
        k_w2t<<<(MB_DIM * NB_CLASSES + 255) / 256, 256, 0, stream>>>(w2, w2t);
        k_main<true><<<BATCH, 256, 0, stream>>>(x, idx, w2t, w2, b2, out);
    } else {
        k_main<false><<<BATCH, 256, 0, stream>>>(x, idx, nullptr, w2, b2, out);
    }
}